// Round 1
// baseline (368.592 us; speedup 1.0000x reference)
//
#include <hip/hip_runtime.h>
#include <stdint.h>

#define S_LEN 4096
#define D_EMB 1024
#define NH 16
#define DHEAD 64
#define N3 3072

typedef __attribute__((ext_vector_type(8))) short short8;
typedef __attribute__((ext_vector_type(4))) float f32x4;

// workspace layout (ushort elements)
#define OFF_XB    0u
#define OFF_WINT  4194304u   // 3072*1024
#define OFF_WOUTT 7340032u   // +1024*1024
#define OFF_Q     8388608u   // q/k/v each 16*4096*64 = 4194304
#define OFF_ATTN  20971520u  // attn out [4096][1024]

__device__ __forceinline__ unsigned short f2bf(float f) {
  unsigned u = __float_as_uint(f);
  unsigned r = u + 0x7FFFu + ((u >> 16) & 1u);
  return (unsigned short)(r >> 16);
}

// ---------------- elementwise f32 -> bf16 ----------------
__global__ __launch_bounds__(256) void cvt_bf16_kernel(const float* __restrict__ src,
                                                       ushort* __restrict__ dst, int n) {
  int i = (blockIdx.x * 256 + threadIdx.x) * 4;
  if (i + 3 < n) {
    float4 v = *(const float4*)(src + i);
    ushort4 o;
    o.x = f2bf(v.x); o.y = f2bf(v.y); o.z = f2bf(v.z); o.w = f2bf(v.w);
    *(ushort4*)(dst + i) = o;
  }
}

// ---------------- transpose + cast: src[R][C] f32 -> dst[C][R] bf16 ----------------
__global__ __launch_bounds__(256) void transpose_cvt_kernel(const float* __restrict__ src,
                                                            ushort* __restrict__ dst,
                                                            int R, int C) {
  __shared__ float tile[32][33];
  int tx = threadIdx.x & 31, ty = threadIdx.x >> 5;  // ty 0..7
  int c0 = blockIdx.x * 32, r0 = blockIdx.y * 32;
#pragma unroll
  for (int i = 0; i < 32; i += 8)
    tile[ty + i][tx] = src[(size_t)(r0 + ty + i) * C + c0 + tx];
  __syncthreads();
#pragma unroll
  for (int i = 0; i < 32; i += 8)
    dst[(size_t)(c0 + ty + i) * R + r0 + tx] = f2bf(tile[tx][ty + i]);
}

// ---------------- GEMM: C[M][N] = A[M][K] * Bt[N][K]^T + bias ----------------
// MODE 0: scatter into q/k/v head-major bf16.  MODE 1: plain f32 out.
#define BK 64
#define LDT 72  // padded stride (144B, multiple of 16B)

template <int MODE>
__global__ __launch_bounds__(256) void gemm_bt_kernel(const ushort* __restrict__ A,
                                                      const ushort* __restrict__ Bt,
                                                      const float* __restrict__ bias,
                                                      ushort* __restrict__ o16,
                                                      float* __restrict__ o32,
                                                      int N, int K) {
  __shared__ ushort As[128 * LDT];
  __shared__ ushort Bs[128 * LDT];
  int tid = threadIdx.x, w = tid >> 6, lane = tid & 63;
  int wr = w >> 1, wc = w & 1;
  int l15 = lane & 15, g = lane >> 4;
  int bm = blockIdx.y * 128, bn = blockIdx.x * 128;
  f32x4 acc[4][4];
#pragma unroll
  for (int m = 0; m < 4; ++m)
#pragma unroll
    for (int n = 0; n < 4; ++n) acc[m][n] = (f32x4){0.f, 0.f, 0.f, 0.f};

  int sr = tid >> 1;            // staging row 0..127
  int sc = (tid & 1) * 32;      // staging col 0 or 32

  for (int k0 = 0; k0 < K; k0 += BK) {
    __syncthreads();
    {
      const ushort* ga = A + (size_t)(bm + sr) * K + k0 + sc;
      const ushort* gb = Bt + (size_t)(bn + sr) * K + k0 + sc;
      short8 ra[4], rb[4];
#pragma unroll
      for (int i = 0; i < 4; ++i) {
        ra[i] = *(const short8*)(ga + i * 8);
        rb[i] = *(const short8*)(gb + i * 8);
      }
#pragma unroll
      for (int i = 0; i < 4; ++i) {
        *(short8*)&As[sr * LDT + sc + i * 8] = ra[i];
        *(short8*)&Bs[sr * LDT + sc + i * 8] = rb[i];
      }
    }
    __syncthreads();
    short8 a[4][2], b[4][2];
#pragma unroll
    for (int m = 0; m < 4; ++m)
#pragma unroll
      for (int t = 0; t < 2; ++t)
        a[m][t] = *(const short8*)&As[(wr * 64 + m * 16 + l15) * LDT + t * 32 + g * 8];
#pragma unroll
    for (int n = 0; n < 4; ++n)
#pragma unroll
      for (int t = 0; t < 2; ++t)
        b[n][t] = *(const short8*)&Bs[(wc * 64 + n * 16 + l15) * LDT + t * 32 + g * 8];
#pragma unroll
    for (int m = 0; m < 4; ++m)
#pragma unroll
      for (int n = 0; n < 4; ++n)
#pragma unroll
        for (int t = 0; t < 2; ++t)
          acc[m][n] = __builtin_amdgcn_mfma_f32_16x16x32_bf16(a[m][t], b[n][t], acc[m][n], 0, 0, 0);
  }

#pragma unroll
  for (int m = 0; m < 4; ++m) {
    int rbase = bm + wr * 64 + m * 16 + g * 4;
#pragma unroll
    for (int n = 0; n < 4; ++n) {
      int c = bn + wc * 64 + n * 16 + l15;
      float bv = bias[c];
      if (MODE == 0) {
        int which = c >> 10, cc = c & 1023, h = cc >> 6, dcol = cc & 63;
        ushort* dst = o16 + (size_t)which * (NH * (size_t)S_LEN * DHEAD) +
                      (size_t)h * (S_LEN * DHEAD) + dcol;
#pragma unroll
        for (int j = 0; j < 4; ++j)
          dst[(size_t)(rbase + j) * DHEAD] = f2bf(acc[m][n][j] + bv);
      } else {
#pragma unroll
        for (int j = 0; j < 4; ++j)
          o32[(size_t)(rbase + j) * N + c] = acc[m][n][j] + bv;
      }
    }
  }
}

// ---------------- causal flash attention ----------------
// q/k/v: [H][S][64] bf16.  out: [S][1024] bf16 at [s][h*64+d].
__global__ __launch_bounds__(256) void attn_kernel(const ushort* __restrict__ Q,
                                                   const ushort* __restrict__ Kg,
                                                   const ushort* __restrict__ Vg,
                                                   ushort* __restrict__ O) {
  __shared__ ushort Ks[64 * LDT];
  __shared__ ushort Vt[64 * LDT];   // transposed: [d][key]
  __shared__ ushort Pl[4][16 * LDT];
  int h = blockIdx.x >> 6, qt = blockIdx.x & 63;
  int q0 = qt * 64;
  int tid = threadIdx.x, w = tid >> 6, lane = tid & 63;
  int l15 = lane & 15, g = lane >> 4;
  const ushort* qh = Q + (size_t)h * (S_LEN * DHEAD);
  const ushort* kh = Kg + (size_t)h * (S_LEN * DHEAD);
  const ushort* vh = Vg + (size_t)h * (S_LEN * DHEAD);

  short8 aq[2];
  {
    int qrow = q0 + w * 16 + l15;
#pragma unroll
    for (int t = 0; t < 2; ++t)
      aq[t] = *(const short8*)&qh[(size_t)qrow * DHEAD + t * 32 + g * 8];
  }
  f32x4 acc_o[4];
#pragma unroll
  for (int dt = 0; dt < 4; ++dt) acc_o[dt] = (f32x4){0.f, 0.f, 0.f, 0.f};
  float mstate[4], lstate[4];
#pragma unroll
  for (int j = 0; j < 4; ++j) { mstate[j] = -1e30f; lstate[j] = 0.f; }
  int qr_base = q0 + w * 16 + g * 4;
  int sr = tid >> 2, scb = (tid & 3) * 16;

  for (int it = 0; it <= qt; ++it) {
    int kv0 = it * 64;
    __syncthreads();
    {
      const ushort* kgp = &kh[(size_t)(kv0 + sr) * DHEAD + scb];
      const ushort* vgp = &vh[(size_t)(kv0 + sr) * DHEAD + scb];
      short8 ka = *(const short8*)kgp;
      short8 kb = *(const short8*)(kgp + 8);
      short8 va = *(const short8*)vgp;
      short8 vb = *(const short8*)(vgp + 8);
      *(short8*)&Ks[sr * LDT + scb] = ka;
      *(short8*)&Ks[sr * LDT + scb + 8] = kb;
#pragma unroll
      for (int i = 0; i < 8; ++i) {
        Vt[(scb + i) * LDT + sr] = (ushort)va[i];
        Vt[(scb + 8 + i) * LDT + sr] = (ushort)vb[i];
      }
    }
    __syncthreads();

    f32x4 accs[4];
#pragma unroll
    for (int ct = 0; ct < 4; ++ct) accs[ct] = (f32x4){0.f, 0.f, 0.f, 0.f};
#pragma unroll
    for (int ct = 0; ct < 4; ++ct)
#pragma unroll
      for (int t = 0; t < 2; ++t) {
        short8 kf = *(const short8*)&Ks[(ct * 16 + l15) * LDT + t * 32 + g * 8];
        accs[ct] = __builtin_amdgcn_mfma_f32_16x16x32_bf16(aq[t], kf, accs[ct], 0, 0, 0);
      }

    float sv[4][4];
#pragma unroll
    for (int ct = 0; ct < 4; ++ct) {
      int key = kv0 + ct * 16 + l15;
#pragma unroll
      for (int j = 0; j < 4; ++j) {
        float s = accs[ct][j] * 0.125f;
        sv[ct][j] = (key > qr_base + j) ? -1e30f : s;
      }
    }
    ushort* pw = Pl[w];
#pragma unroll
    for (int j = 0; j < 4; ++j) {
      float mx = fmaxf(fmaxf(sv[0][j], sv[1][j]), fmaxf(sv[2][j], sv[3][j]));
#pragma unroll
      for (int off = 1; off < 16; off <<= 1) mx = fmaxf(mx, __shfl_xor(mx, off));
      float mnew = fmaxf(mstate[j], mx);
      float corr = __expf(mstate[j] - mnew);
      float rs = 0.f;
#pragma unroll
      for (int ct = 0; ct < 4; ++ct) {
        float p = __expf(sv[ct][j] - mnew);
        sv[ct][j] = p;
        rs += p;
      }
#pragma unroll
      for (int off = 1; off < 16; off <<= 1) rs += __shfl_xor(rs, off);
      mstate[j] = mnew;
      lstate[j] = lstate[j] * corr + rs;
#pragma unroll
      for (int dt = 0; dt < 4; ++dt) acc_o[dt][j] *= corr;
    }
#pragma unroll
    for (int ct = 0; ct < 4; ++ct)
#pragma unroll
      for (int j = 0; j < 4; ++j)
        pw[(g * 4 + j) * LDT + ct * 16 + l15] = f2bf(sv[ct][j]);
    __syncthreads();  // cross-lane P visibility before PV
#pragma unroll
    for (int dt = 0; dt < 4; ++dt)
#pragma unroll
      for (int t = 0; t < 2; ++t) {
        short8 pa = *(const short8*)&pw[l15 * LDT + t * 32 + g * 8];
        short8 vf = *(const short8*)&Vt[(dt * 16 + l15) * LDT + t * 32 + g * 8];
        acc_o[dt] = __builtin_amdgcn_mfma_f32_16x16x32_bf16(pa, vf, acc_o[dt], 0, 0, 0);
      }
  }

#pragma unroll
  for (int dt = 0; dt < 4; ++dt)
#pragma unroll
    for (int j = 0; j < 4; ++j) {
      float ov = acc_o[dt][j] * (1.f / lstate[j]);
      int row = qr_base + j;
      O[(size_t)row * D_EMB + h * DHEAD + dt * 16 + l15] = f2bf(ov);
    }
}

extern "C" void kernel_launch(void* const* d_in, const int* in_sizes, int n_in,
                              void* d_out, int out_size, void* d_ws, size_t ws_size,
                              hipStream_t stream) {
  const float* x = (const float*)d_in[0];
  const float* W_in = (const float*)d_in[1];
  const float* b_in = (const float*)d_in[2];
  const float* W_out = (const float*)d_in[3];
  const float* b_out = (const float*)d_in[4];
  float* out = (float*)d_out;
  ushort* ws = (ushort*)d_ws;

  // 1. x -> bf16
  cvt_bf16_kernel<<<4096, 256, 0, stream>>>(x, ws + OFF_XB, S_LEN * D_EMB);
  // 2. W_in^T, W_out^T -> bf16
  transpose_cvt_kernel<<<dim3(N3 / 32, D_EMB / 32), 256, 0, stream>>>(W_in, ws + OFF_WINT, D_EMB, N3);
  transpose_cvt_kernel<<<dim3(D_EMB / 32, D_EMB / 32), 256, 0, stream>>>(W_out, ws + OFF_WOUTT, D_EMB, D_EMB);
  // 3. qkv = x @ W_in + b_in, scattered to head-major q/k/v
  gemm_bt_kernel<0><<<dim3(N3 / 128, S_LEN / 128), 256, 0, stream>>>(
      ws + OFF_XB, ws + OFF_WINT, b_in, ws + OFF_Q, nullptr, N3, D_EMB);
  // 4. causal attention
  attn_kernel<<<NH * (S_LEN / 64), 256, 0, stream>>>(
      ws + OFF_Q, ws + OFF_Q + 4194304u, ws + OFF_Q + 8388608u, ws + OFF_ATTN);
  // 5. out = attn @ W_out + b_out
  gemm_bt_kernel<1><<<dim3(D_EMB / 128, S_LEN / 128), 256, 0, stream>>>(
      ws + OFF_ATTN, ws + OFF_WOUTT, b_out, nullptr, out, D_EMB, D_EMB);
}

// Round 2
// 227.367 us; speedup vs baseline: 1.6211x; 1.6211x over previous
//
#include <hip/hip_runtime.h>
#include <stdint.h>

#define S_LEN 4096
#define D_EMB 1024
#define NH 16
#define DHEAD 64
#define N3 3072

typedef __attribute__((ext_vector_type(8))) short short8;
typedef __attribute__((ext_vector_type(4))) float f32x4;

// workspace layout (ushort elements)
#define OFF_XB    0u
#define OFF_WINT  4194304u   // 3072*1024
#define OFF_WOUTT 7340032u   // +1024*1024
#define OFF_Q     8388608u   // q [H][S][64], k [H][S][64], v^T [H][64][S], each 4194304
#define OFF_ATTN  20971520u  // attn out [4096][1024]

__device__ __forceinline__ unsigned short f2bf(float f) {
  unsigned u = __float_as_uint(f);
  unsigned r = u + 0x7FFFu + ((u >> 16) & 1u);
  return (unsigned short)(r >> 16);
}

// ---------------- elementwise f32 -> bf16 ----------------
__global__ __launch_bounds__(256) void cvt_bf16_kernel(const float* __restrict__ src,
                                                       ushort* __restrict__ dst, int n) {
  int i = (blockIdx.x * 256 + threadIdx.x) * 4;
  if (i + 3 < n) {
    float4 v = *(const float4*)(src + i);
    ushort4 o;
    o.x = f2bf(v.x); o.y = f2bf(v.y); o.z = f2bf(v.z); o.w = f2bf(v.w);
    *(ushort4*)(dst + i) = o;
  }
}

// ---------------- transpose + cast: src[R][C] f32 -> dst[C][R] bf16 ----------------
__global__ __launch_bounds__(256) void transpose_cvt_kernel(const float* __restrict__ src,
                                                            ushort* __restrict__ dst,
                                                            int R, int C) {
  __shared__ float tile[32][33];
  int tx = threadIdx.x & 31, ty = threadIdx.x >> 5;  // ty 0..7
  int c0 = blockIdx.x * 32, r0 = blockIdx.y * 32;
#pragma unroll
  for (int i = 0; i < 32; i += 8)
    tile[ty + i][tx] = src[(size_t)(r0 + ty + i) * C + c0 + tx];
  __syncthreads();
#pragma unroll
  for (int i = 0; i < 32; i += 8)
    dst[(size_t)(c0 + ty + i) * R + r0 + tx] = f2bf(tile[tx][ty + i]);
}

// ---------------- GEMM: C[M][N] = A[M][K] * Bt[N][K]^T + bias ----------------
// MODE 0: scatter into q/k head-major bf16 + v TRANSPOSED ([H][64][S]).
// MODE 1: plain f32 out.
#define BK 64
#define LDT 72  // padded stride (144B, multiple of 16B)

template <int MODE>
__global__ __launch_bounds__(256) void gemm_bt_kernel(const ushort* __restrict__ A,
                                                      const ushort* __restrict__ Bt,
                                                      const float* __restrict__ bias,
                                                      ushort* __restrict__ o16,
                                                      float* __restrict__ o32,
                                                      int N, int K) {
  __shared__ ushort As[128 * LDT];
  __shared__ ushort Bs[128 * LDT];
  int tid = threadIdx.x, w = tid >> 6, lane = tid & 63;
  int wr = w >> 1, wc = w & 1;
  int l15 = lane & 15, g = lane >> 4;
  int bm = blockIdx.y * 128, bn = blockIdx.x * 128;
  f32x4 acc[4][4];
#pragma unroll
  for (int m = 0; m < 4; ++m)
#pragma unroll
    for (int n = 0; n < 4; ++n) acc[m][n] = (f32x4){0.f, 0.f, 0.f, 0.f};

  int sr = tid >> 1;            // staging row 0..127
  int sc = (tid & 1) * 32;      // staging col 0 or 32

  for (int k0 = 0; k0 < K; k0 += BK) {
    __syncthreads();
    {
      const ushort* ga = A + (size_t)(bm + sr) * K + k0 + sc;
      const ushort* gb = Bt + (size_t)(bn + sr) * K + k0 + sc;
      short8 ra[4], rb[4];
#pragma unroll
      for (int i = 0; i < 4; ++i) {
        ra[i] = *(const short8*)(ga + i * 8);
        rb[i] = *(const short8*)(gb + i * 8);
      }
#pragma unroll
      for (int i = 0; i < 4; ++i) {
        *(short8*)&As[sr * LDT + sc + i * 8] = ra[i];
        *(short8*)&Bs[sr * LDT + sc + i * 8] = rb[i];
      }
    }
    __syncthreads();
    short8 a[4][2], b[4][2];
#pragma unroll
    for (int m = 0; m < 4; ++m)
#pragma unroll
      for (int t = 0; t < 2; ++t)
        a[m][t] = *(const short8*)&As[(wr * 64 + m * 16 + l15) * LDT + t * 32 + g * 8];
#pragma unroll
    for (int n = 0; n < 4; ++n)
#pragma unroll
      for (int t = 0; t < 2; ++t)
        b[n][t] = *(const short8*)&Bs[(wc * 64 + n * 16 + l15) * LDT + t * 32 + g * 8];
#pragma unroll
    for (int m = 0; m < 4; ++m)
#pragma unroll
      for (int n = 0; n < 4; ++n)
#pragma unroll
        for (int t = 0; t < 2; ++t)
          acc[m][n] = __builtin_amdgcn_mfma_f32_16x16x32_bf16(a[m][t], b[n][t], acc[m][n], 0, 0, 0);
  }

#pragma unroll
  for (int m = 0; m < 4; ++m) {
    int rbase = bm + wr * 64 + m * 16 + g * 4;
#pragma unroll
    for (int n = 0; n < 4; ++n) {
      int c = bn + wc * 64 + n * 16 + l15;
      float bv = bias[c];
      if (MODE == 0) {
        int which = c >> 10, cc = c & 1023, hh = cc >> 6, dcol = cc & 63;
        if (which == 2) {
          // v transposed: [H][64][S]
          ushort4 o;
          o.x = f2bf(acc[m][n][0] + bv);
          o.y = f2bf(acc[m][n][1] + bv);
          o.z = f2bf(acc[m][n][2] + bv);
          o.w = f2bf(acc[m][n][3] + bv);
          *(ushort4*)&o16[8388608u + (size_t)hh * (DHEAD * (size_t)S_LEN) +
                          (size_t)dcol * S_LEN + rbase] = o;
        } else {
          ushort* dst = o16 + (size_t)which * 4194304u +
                        (size_t)hh * (S_LEN * DHEAD) + dcol;
#pragma unroll
          for (int j = 0; j < 4; ++j)
            dst[(size_t)(rbase + j) * DHEAD] = f2bf(acc[m][n][j] + bv);
        }
      } else {
#pragma unroll
        for (int j = 0; j < 4; ++j)
          o32[(size_t)(rbase + j) * N + c] = acc[m][n][j] + bv;
      }
    }
  }
}

// ---------------- causal flash attention ----------------
// Q,K: [H][S][64] bf16.  Vt: [H][64][S] bf16.  O: [S][1024] bf16.
// Grid: NH*32 blocks; block (h, p) handles q-tiles {p, 63-p} (work balance).
__global__ __launch_bounds__(256) void attn_kernel(const ushort* __restrict__ Q,
                                                   const ushort* __restrict__ Kg,
                                                   const ushort* __restrict__ Vtg,
                                                   ushort* __restrict__ O) {
  __shared__ ushort Ks[64 * LDT];
  __shared__ ushort Vs[64 * LDT];   // [d][key]
  __shared__ ushort Pl[4][16 * LDT];
  int h = blockIdx.x >> 5, p = blockIdx.x & 31;
  int tid = threadIdx.x, w = tid >> 6, lane = tid & 63;
  int l15 = lane & 15, g = lane >> 4;
  const ushort* qh = Q + (size_t)h * (S_LEN * DHEAD);
  const ushort* kh = Kg + (size_t)h * (S_LEN * DHEAD);
  const ushort* vh = Vtg + (size_t)h * (DHEAD * (size_t)S_LEN);
  int sr = tid >> 2;           // 0..63
  int scc = (tid & 3) * 16;    // 0,16,32,48
  ushort* pw = Pl[w];

#pragma unroll 1
  for (int half = 0; half < 2; ++half) {
    int qt = half ? (63 - p) : p;
    int q0 = qt * 64;
    short8 aq[2];
    {
      int qrow = q0 + w * 16 + l15;
#pragma unroll
      for (int t = 0; t < 2; ++t)
        aq[t] = *(const short8*)&qh[(size_t)qrow * DHEAD + t * 32 + g * 8];
    }
    f32x4 acc_o[4];
#pragma unroll
    for (int dt = 0; dt < 4; ++dt) acc_o[dt] = (f32x4){0.f, 0.f, 0.f, 0.f};
    float mstate[4], lstate[4];
#pragma unroll
    for (int j = 0; j < 4; ++j) { mstate[j] = -1e30f; lstate[j] = 0.f; }
    int qr_base = q0 + w * 16 + g * 4;

    // prologue: stage tile 0
    {
      short8 ka = *(const short8*)&kh[(size_t)sr * DHEAD + scc];
      short8 kb = *(const short8*)&kh[(size_t)sr * DHEAD + scc + 8];
      short8 va = *(const short8*)&vh[(size_t)sr * S_LEN + scc];
      short8 vb = *(const short8*)&vh[(size_t)sr * S_LEN + scc + 8];
      __syncthreads();   // previous half's readers done
      *(short8*)&Ks[sr * LDT + scc] = ka;
      *(short8*)&Ks[sr * LDT + scc + 8] = kb;
      *(short8*)&Vs[sr * LDT + scc] = va;
      *(short8*)&Vs[sr * LDT + scc + 8] = vb;
      __syncthreads();
    }

    for (int it = 0; it <= qt; ++it) {
      int kv0 = it * 64;
      bool more = (it < qt);
      short8 nka, nkb, nva, nvb;
      if (more) {
        int kv1 = kv0 + 64;
        nka = *(const short8*)&kh[(size_t)(kv1 + sr) * DHEAD + scc];
        nkb = *(const short8*)&kh[(size_t)(kv1 + sr) * DHEAD + scc + 8];
        nva = *(const short8*)&vh[(size_t)sr * S_LEN + kv1 + scc];
        nvb = *(const short8*)&vh[(size_t)sr * S_LEN + kv1 + scc + 8];
      }

      // QK^T
      f32x4 accs[4];
#pragma unroll
      for (int ct = 0; ct < 4; ++ct) accs[ct] = (f32x4){0.f, 0.f, 0.f, 0.f};
#pragma unroll
      for (int ct = 0; ct < 4; ++ct)
#pragma unroll
        for (int t = 0; t < 2; ++t) {
          short8 kf = *(const short8*)&Ks[(ct * 16 + l15) * LDT + t * 32 + g * 8];
          accs[ct] = __builtin_amdgcn_mfma_f32_16x16x32_bf16(aq[t], kf, accs[ct], 0, 0, 0);
        }

      float sv[4][4];
      if (it == qt) {
#pragma unroll
        for (int ct = 0; ct < 4; ++ct) {
          int key = kv0 + ct * 16 + l15;
#pragma unroll
          for (int j = 0; j < 4; ++j) {
            float s = accs[ct][j] * 0.125f;
            sv[ct][j] = (key > qr_base + j) ? -1e30f : s;
          }
        }
      } else {
#pragma unroll
        for (int ct = 0; ct < 4; ++ct)
#pragma unroll
          for (int j = 0; j < 4; ++j) sv[ct][j] = accs[ct][j] * 0.125f;
      }

#pragma unroll
      for (int j = 0; j < 4; ++j) {
        float mx = fmaxf(fmaxf(sv[0][j], sv[1][j]), fmaxf(sv[2][j], sv[3][j]));
#pragma unroll
        for (int off = 1; off < 16; off <<= 1) mx = fmaxf(mx, __shfl_xor(mx, off));
        float mnew = fmaxf(mstate[j], mx);
        float corr = __expf(mstate[j] - mnew);
        float rs = 0.f;
#pragma unroll
        for (int ct = 0; ct < 4; ++ct) {
          float pexp = __expf(sv[ct][j] - mnew);
          sv[ct][j] = pexp;
          rs += pexp;
        }
#pragma unroll
        for (int off = 1; off < 16; off <<= 1) rs += __shfl_xor(rs, off);
        mstate[j] = mnew;
        lstate[j] = lstate[j] * corr + rs;
#pragma unroll
        for (int dt = 0; dt < 4; ++dt) acc_o[dt][j] *= corr;
      }
#pragma unroll
      for (int ct = 0; ct < 4; ++ct)
#pragma unroll
        for (int j = 0; j < 4; ++j)
          pw[(g * 4 + j) * LDT + ct * 16 + l15] = f2bf(sv[ct][j]);
      // P is wave-private: no block barrier needed, just drain LDS writes.
      asm volatile("s_waitcnt lgkmcnt(0)" ::: "memory");

#pragma unroll
      for (int dt = 0; dt < 4; ++dt)
#pragma unroll
        for (int t = 0; t < 2; ++t) {
          short8 pa = *(const short8*)&pw[l15 * LDT + t * 32 + g * 8];
          short8 vf = *(const short8*)&Vs[(dt * 16 + l15) * LDT + t * 32 + g * 8];
          acc_o[dt] = __builtin_amdgcn_mfma_f32_16x16x32_bf16(pa, vf, acc_o[dt], 0, 0, 0);
        }

      __syncthreads();   // all waves done reading Ks/Vs
      if (more) {
        *(short8*)&Ks[sr * LDT + scc] = nka;
        *(short8*)&Ks[sr * LDT + scc + 8] = nkb;
        *(short8*)&Vs[sr * LDT + scc] = nva;
        *(short8*)&Vs[sr * LDT + scc + 8] = nvb;
        __syncthreads();
      }
    }

#pragma unroll
    for (int dt = 0; dt < 4; ++dt) {
#pragma unroll
      for (int j = 0; j < 4; ++j) {
        float ov = acc_o[dt][j] * (1.f / lstate[j]);
        int row = qr_base + j;
        O[(size_t)row * D_EMB + h * DHEAD + dt * 16 + l15] = f2bf(ov);
      }
    }
  }
}

extern "C" void kernel_launch(void* const* d_in, const int* in_sizes, int n_in,
                              void* d_out, int out_size, void* d_ws, size_t ws_size,
                              hipStream_t stream) {
  const float* x = (const float*)d_in[0];
  const float* W_in = (const float*)d_in[1];
  const float* b_in = (const float*)d_in[2];
  const float* W_out = (const float*)d_in[3];
  const float* b_out = (const float*)d_in[4];
  float* out = (float*)d_out;
  ushort* ws = (ushort*)d_ws;

  // 1. x -> bf16
  cvt_bf16_kernel<<<4096, 256, 0, stream>>>(x, ws + OFF_XB, S_LEN * D_EMB);
  // 2. W_in^T, W_out^T -> bf16
  transpose_cvt_kernel<<<dim3(N3 / 32, D_EMB / 32), 256, 0, stream>>>(W_in, ws + OFF_WINT, D_EMB, N3);
  transpose_cvt_kernel<<<dim3(D_EMB / 32, D_EMB / 32), 256, 0, stream>>>(W_out, ws + OFF_WOUTT, D_EMB, D_EMB);
  // 3. qkv = x @ W_in + b_in, scattered to q/k head-major + v transposed
  gemm_bt_kernel<0><<<dim3(N3 / 128, S_LEN / 128), 256, 0, stream>>>(
      ws + OFF_XB, ws + OFF_WINT, b_in, ws + OFF_Q, nullptr, N3, D_EMB);
  // 4. causal attention (pair-balanced grid)
  attn_kernel<<<NH * 32, 256, 0, stream>>>(
      ws + OFF_Q, ws + OFF_Q + 4194304u, ws + OFF_Q + 8388608u, ws + OFF_ATTN);
  // 5. out = attn @ W_out + b_out
  gemm_bt_kernel<1><<<dim3(D_EMB / 128, S_LEN / 128), 256, 0, stream>>>(
      ws + OFF_ATTN, ws + OFF_WOUTT, b_out, nullptr, out, D_EMB, D_EMB);
}